// Round 3
// baseline (608.028 us; speedup 1.0000x reference)
//
#include <hip/hip_runtime.h>
#include <hip/hip_bf16.h>
#include <math.h>

// Problem constants
#define BATCH 1024
#define NREAL 784
#define NPAD  896      // 7*128, zero-padded graph dim
#define C1D   32
#define C2D   32
#define HDIM  512
#define NCLS  10
#define KFC   25088    // 784*32

#define KS_G1 4        // split-K for G1 (K=896 -> 224/slice, 7 iters)
#define KS_FC 16       // split-K for fc1 (K=25088 -> 1568/slice, 49 iters)

// GEMM tile
#define BM 128
#define BN 128
#define BK 32

using bf16x8  = __attribute__((ext_vector_type(8))) __bf16;
using floatx4 = __attribute__((ext_vector_type(4))) float;

__device__ __forceinline__ float elu_f(float t) {
    return t > 0.f ? t : (__expf(t) - 1.f);
}

// LDS-only barrier: waits ds ops but leaves global loads (vmcnt) in flight.
// __syncthreads() would emit s_waitcnt vmcnt(0) and drain the prefetch queue.
__device__ __forceinline__ void wg_barrier_lds() {
    asm volatile("s_waitcnt lgkmcnt(0)\n\ts_barrier" ::: "memory");
}

// ---------------------------------------------------------------------------
// BT-GEMM, register-staged pipeline:
//   global_load_dwordx4 (prefetch distance 2, stays in flight across barriers)
//     -> VGPR -> ds_write_b128 -> LDS double buffer -> ds_read_b128 -> MFMA
// One lgkm-only barrier per k-iter. C[row][col] = sum_k A[row][k]*Bm[col][k].
// 128x128 tile, 256 thr (4 waves, 2x2 of 64x64), BK=32, mfma 16x16x32 bf16.
// MODE 1: elu(acc+bias[col&31]) -> bf16 outH[(col>>5)*KFC+row*32+(col&31)],
//         masked to row<784                                           (G3)
// MODE 2: fp32 partial store outF[z*sliceStride + row*ldc + col]   (G1, G4)
// ---------------------------------------------------------------------------
template<int MODE>
__launch_bounds__(256)
__global__ void gemm_bt(const __hip_bfloat16* __restrict__ A, int lda,
                        const __hip_bfloat16* __restrict__ Bm, int ldb,
                        int kIters, int kPerZ, size_t sliceStride,
                        float* __restrict__ outF, int ldc,
                        __hip_bfloat16* __restrict__ outH,
                        const float* __restrict__ bias)
{
    __shared__ __align__(16) __hip_bfloat16 As[2][BM * BK];
    __shared__ __align__(16) __hip_bfloat16 Bs[2][BN * BK];

    const int tid  = threadIdx.x;
    const int lane = tid & 63;
    const int wave = tid >> 6;
    const int wi = wave >> 1, wj = wave & 1;

    const int m0 = blockIdx.y * BM;
    const int n0 = blockIdx.x * BN;
    const int kBase = blockIdx.z * kPerZ;

    const int rowInChunk = lane >> 2;       // 16 rows per 1KB chunk
    const int kOff8 = (lane & 3) * 8;       // 4 lanes cover 32 bf16 per row

    // per-thread global source pointers (advance by BK each stage)
    const __hip_bfloat16* aSrc[2];
    const __hip_bfloat16* bSrc[2];
    #pragma unroll
    for (int c = 0; c < 2; c++) {
        const int r = (wave * 2 + c) * 16 + rowInChunk;
        aSrc[c] = A  + (size_t)(m0 + r) * lda + kBase + kOff8;
        bSrc[c] = Bm + (size_t)(n0 + r) * ldb + kBase + kOff8;
    }
    // per-thread LDS write offset (elements): chunk*512 + lane*8
    const int ldsW[2] = { (wave * 2 + 0) * 512 + lane * 8,
                          (wave * 2 + 1) * 512 + lane * 8 };

    floatx4 acc[4][4];
    const floatx4 zero4 = {0.f, 0.f, 0.f, 0.f};
    #pragma unroll
    for (int i = 0; i < 4; i++)
        #pragma unroll
        for (int j = 0; j < 4; j++) acc[i][j] = zero4;

    int4 sa[2][2], sb[2][2];   // staging regs [stage parity][chunk]

    // prologue: load stage 0 and stage 1; write stage 0 to LDS buf 0
    #pragma unroll
    for (int c = 0; c < 2; c++) {
        sa[0][c] = *(const int4*)aSrc[c];
        sb[0][c] = *(const int4*)bSrc[c];
        aSrc[c] += BK; bSrc[c] += BK;
    }
    if (kIters > 1) {
        #pragma unroll
        for (int c = 0; c < 2; c++) {
            sa[1][c] = *(const int4*)aSrc[c];
            sb[1][c] = *(const int4*)bSrc[c];
            aSrc[c] += BK; bSrc[c] += BK;
        }
    }
    #pragma unroll
    for (int c = 0; c < 2; c++) {
        *(int4*)(&As[0][ldsW[c]]) = sa[0][c];
        *(int4*)(&Bs[0][ldsW[c]]) = sb[0][c];
    }
    wg_barrier_lds();

    for (int kt = 0; kt < kIters; kt += 2) {
        #pragma unroll
        for (int u = 0; u < 2; u++) {           // constant parity per body
            const int k = kt + u;
            if (k >= kIters) break;
            const int buf = u;                   // k&1 == u (kt even)

            bf16x8 af[4], bfr[4];
            #pragma unroll
            for (int mi = 0; mi < 4; mi++)
                af[mi] = *(const bf16x8*)(&As[buf][(wi * 64 + mi * 16 + (lane & 15)) * BK + (lane >> 4) * 8]);
            #pragma unroll
            for (int nj = 0; nj < 4; nj++)
                bfr[nj] = *(const bf16x8*)(&Bs[buf][(wj * 64 + nj * 16 + (lane & 15)) * BK + (lane >> 4) * 8]);

            // prefetch stage k+2 into parity u (just moved to LDS)
            if (k + 2 < kIters) {
                #pragma unroll
                for (int c = 0; c < 2; c++) {
                    sa[u][c] = *(const int4*)aSrc[c];
                    sb[u][c] = *(const int4*)bSrc[c];
                    aSrc[c] += BK; bSrc[c] += BK;
                }
            }
            // stage k+1 regs -> LDS buf^1 (compiler inserts fine vmcnt here)
            if (k + 1 < kIters) {
                #pragma unroll
                for (int c = 0; c < 2; c++) {
                    *(int4*)(&As[buf ^ 1][ldsW[c]]) = sa[u ^ 1][c];
                    *(int4*)(&Bs[buf ^ 1][ldsW[c]]) = sb[u ^ 1][c];
                }
            }

            #pragma unroll
            for (int mi = 0; mi < 4; mi++)
                #pragma unroll
                for (int nj = 0; nj < 4; nj++)
                    acc[mi][nj] = __builtin_amdgcn_mfma_f32_16x16x32_bf16(af[mi], bfr[nj], acc[mi][nj], 0, 0, 0);

            wg_barrier_lds();   // lgkm only — global prefetch stays in flight
        }
    }

    // epilogue: C/D layout col=lane&15, row=(lane>>4)*4+reg  [verified m89/m91]
    #pragma unroll
    for (int mi = 0; mi < 4; mi++) {
        #pragma unroll
        for (int nj = 0; nj < 4; nj++) {
            #pragma unroll
            for (int r = 0; r < 4; r++) {
                const int row = m0 + wi * 64 + mi * 16 + (lane >> 4) * 4 + r;
                const int col = n0 + wj * 64 + nj * 16 + (lane & 15);
                const float v = acc[mi][nj][r];
                if (MODE == 1) {
                    if (row < NREAL) {
                        const int c = col & 31, b = col >> 5;
                        const float t = elu_f(v + bias[c]);
                        outH[(size_t)b * KFC + row * 32 + c] = __float2bfloat16(t);
                    }
                } else {
                    outF[(size_t)blockIdx.z * sliceStride + (size_t)row * ldc + col] = v;
                }
            }
        }
    }
}

// ---------------------------------------------------------------------------
// Conversions / padding
// ---------------------------------------------------------------------------
__global__ void convX(const float* __restrict__ x, __hip_bfloat16* __restrict__ Xbf) {
    const int idx = blockIdx.x * 256 + threadIdx.x;
    if (idx >= BATCH * NPAD) return;
    const int m = idx % NPAD, b = idx / NPAD;
    const float v = (m < NREAL) ? x[(size_t)b * NREAL + m] : 0.f;
    Xbf[idx] = __float2bfloat16(v);
}

__global__ void convA(const float* __restrict__ a, __hip_bfloat16* __restrict__ Abf) {
    const int idx = blockIdx.x * 256 + threadIdx.x;
    if (idx >= NPAD * NPAD) return;
    const int m = idx % NPAD, n = idx / NPAD;
    const float v = (m < NREAL && n < NREAL) ? a[(size_t)n * NREAL + m] : 0.f;
    Abf[idx] = __float2bfloat16(v);
}

// wf1 [25088][512] fp32 -> Wt [512][25088] bf16 (LDS tile transpose)
__global__ void convW(const float* __restrict__ wf1, __hip_bfloat16* __restrict__ Wt) {
    __shared__ float tile[32][33];
    const int k0 = blockIdx.x * 32, h0 = blockIdx.y * 32;
    const int tx = threadIdx.x, ty = threadIdx.y;  // (32,8)
    #pragma unroll
    for (int i = 0; i < 4; i++)
        tile[ty * 4 + i][tx] = wf1[(size_t)(k0 + ty * 4 + i) * HDIM + h0 + tx];
    __syncthreads();
    #pragma unroll
    for (int i = 0; i < 4; i++)
        Wt[(size_t)(h0 + ty * 4 + i) * KFC + k0 + tx] = __float2bfloat16(tile[tx][ty * 4 + i]);
}

// ---------------------------------------------------------------------------
// Layer-1 fused pointwise: reduce 4 Y split-K partials, then
// T_t[(b*32+c)][m] = sum_c' elu(Y[b][m]*w1[c']+b1[c'])*W2[c'][c]
// ---------------------------------------------------------------------------
__global__ void layer1_fuse(const float* __restrict__ Ypart,
                            const float* __restrict__ w1, const float* __restrict__ b1,
                            const float* __restrict__ w2,
                            __hip_bfloat16* __restrict__ Tt)
{
    __shared__ __align__(16) float sW2[C1D * C2D];
    __shared__ float sw1[C1D], sb1[C1D];
    const int tid = threadIdx.x;                 // 128 threads
    for (int i = tid; i < C1D * C2D; i += 128) sW2[i] = w2[i];
    if (tid < C1D) { sw1[tid] = w1[tid]; sb1[tid] = b1[tid]; }
    __syncthreads();

    const int m = blockIdx.x * 128 + tid;        // 0..895
    const int b = blockIdx.y;
    float y = 0.f;
    #pragma unroll
    for (int z = 0; z < KS_G1; z++)
        y += Ypart[(size_t)z * (BATCH * NPAD) + (size_t)b * NPAD + m];

    float h[C1D];
    #pragma unroll
    for (int c1 = 0; c1 < C1D; c1++) h[c1] = elu_f(y * sw1[c1] + sb1[c1]);

    float4 t4[8];
    #pragma unroll
    for (int q = 0; q < 8; q++) t4[q] = make_float4(0.f, 0.f, 0.f, 0.f);
    #pragma unroll
    for (int c1 = 0; c1 < C1D; c1++) {
        const float hv = h[c1];
        const float4* row = (const float4*)(sW2 + c1 * C2D);
        #pragma unroll
        for (int q = 0; q < 8; q++) {
            const float4 w = row[q];
            t4[q].x += hv * w.x; t4[q].y += hv * w.y;
            t4[q].z += hv * w.z; t4[q].w += hv * w.w;
        }
    }
    const float* tf = (const float*)t4;
    #pragma unroll
    for (int c = 0; c < C2D; c++)
        Tt[((size_t)(b * 32 + c)) * NPAD + m] = __float2bfloat16(tf[c]);
}

// ---------------------------------------------------------------------------
// fc1 reduce (split-K partials) + relu + fc2 + softmax, fused.
// One wave per batch row; lane covers 8 h-values.
// ---------------------------------------------------------------------------
__global__ void fc2_softmax(const float* __restrict__ part, const float* __restrict__ bf1,
                            const float* __restrict__ wf2, const float* __restrict__ bf2,
                            float* __restrict__ out)
{
    __shared__ float sW[HDIM * NCLS];
    __shared__ float sb[NCLS];
    const int tid = threadIdx.x;                 // 256
    for (int i = tid; i < HDIM * NCLS; i += 256) sW[i] = wf2[i];
    if (tid < NCLS) sb[tid] = bf2[tid];
    __syncthreads();

    const int lane = tid & 63, wave = tid >> 6;
    const int b = blockIdx.x * 4 + wave;

    float acc[NCLS];
    #pragma unroll
    for (int c = 0; c < NCLS; c++) acc[c] = 0.f;
    #pragma unroll
    for (int q = 0; q < 8; q++) {
        const int h = q * 64 + lane;
        float hv = bf1[h];
        #pragma unroll
        for (int z = 0; z < KS_FC; z++)
            hv += part[(size_t)z * (BATCH * HDIM) + (size_t)b * HDIM + h];
        hv = hv > 0.f ? hv : 0.f;
        #pragma unroll
        for (int c = 0; c < NCLS; c++) acc[c] += hv * sW[h * NCLS + c];
    }
    #pragma unroll
    for (int c = 0; c < NCLS; c++) {
        #pragma unroll
        for (int off = 32; off >= 1; off >>= 1) acc[c] += __shfl_down(acc[c], off);
    }
    if (lane == 0) {
        float mx = -1e30f;
        #pragma unroll
        for (int c = 0; c < NCLS; c++) { acc[c] += sb[c]; mx = fmaxf(mx, acc[c]); }
        float e[NCLS], s = 0.f;
        #pragma unroll
        for (int c = 0; c < NCLS; c++) { e[c] = __expf(acc[c] - mx); s += e[c]; }
        const float inv = 1.f / s;
        #pragma unroll
        for (int c = 0; c < NCLS; c++) out[(size_t)b * NCLS + c] = e[c] * inv;
    }
}

// ---------------------------------------------------------------------------
// Workspace layout (peak ~113.5 MB; proven ws >= 121.4 MB)
//   h2f   [0,          51380224)  bf16 1024x25088  (written G3, read G4)
//     Ypart [0, 14680064) f32 4x1024x896 — overlay, dead before G3 writes h2f
//   Tt    [51380224,  110100480)  bf16 32768x896   (dead after G3)
//     Wt   [51380224, 77070336)   bf16 512x25088 — overlay after G3
//     part [77070336, 110624768)  f32 16x1024x512 — overlay after G3
//            (spills 0.5 MB into Abf region; Abf dead after G3)
//   Abf   [110100480, 111706112)  bf16 896x896     (dead after G3)
//   Xbf   [111706112, 113541120)  bf16 1024x896    (dead after G1)
// ---------------------------------------------------------------------------
extern "C" void kernel_launch(void* const* d_in, const int* in_sizes, int n_in,
                              void* d_out, int out_size, void* d_ws, size_t ws_size,
                              hipStream_t stream)
{
    const float* x   = (const float*)d_in[0];
    const float* a   = (const float*)d_in[1];
    const float* w1  = (const float*)d_in[2];
    const float* b1  = (const float*)d_in[3];
    const float* w2  = (const float*)d_in[4];
    const float* b2  = (const float*)d_in[5];
    const float* wf1 = (const float*)d_in[6];
    const float* bf1 = (const float*)d_in[7];
    const float* wf2 = (const float*)d_in[8];
    const float* bf2 = (const float*)d_in[9];
    float* out = (float*)d_out;

    char* ws = (char*)d_ws;
    __hip_bfloat16* h2f  = (__hip_bfloat16*)(ws + 0);
    float*          Ypart= (float*)(ws + 0);                  // overlay (pre-G3)
    __hip_bfloat16* Tt   = (__hip_bfloat16*)(ws + 51380224);
    __hip_bfloat16* Wt   = (__hip_bfloat16*)(ws + 51380224);  // overlay (post-G3)
    float*          part = (float*)(ws + 77070336);           // overlay (post-G3)
    __hip_bfloat16* Abf  = (__hip_bfloat16*)(ws + 110100480);
    __hip_bfloat16* Xbf  = (__hip_bfloat16*)(ws + 111706112);

    convX<<<(BATCH * NPAD + 255) / 256, 256, 0, stream>>>(x, Xbf);
    convA<<<(NPAD * NPAD + 255) / 256, 256, 0, stream>>>(a, Abf);

    // G1: Ypart[z][b][n] partials of sum_m Xbf[b][m]*Abf[n][m]
    //     (M=1024, N=896, K=224/slice, split-K=4 -> 224 blocks)
    gemm_bt<2><<<dim3(NPAD / BN, BATCH / BM, KS_G1), 256, 0, stream>>>(
        Xbf, NPAD, Abf, NPAD, (NPAD / KS_G1) / BK, NPAD / KS_G1,
        (size_t)BATCH * NPAD, Ypart, NPAD, nullptr, nullptr);

    // layer-1 pointwise + @W2, transposed store (reduces Ypart internally)
    layer1_fuse<<<dim3(NPAD / 128, BATCH), 128, 0, stream>>>(Ypart, w1, b1, w2, Tt);

    // G3: h2 = elu(A @ T + b2);  C[n][(b,c)] (M=896, N=32768, K=896 -> 1792 blocks)
    gemm_bt<1><<<dim3((BATCH * 32) / BN, NPAD / BM, 1), 256, 0, stream>>>(
        Abf, NPAD, Tt, NPAD, NPAD / BK, 0, 0, nullptr, 0, h2f, b2);

    // transpose wf1 -> bf16 (into the now-dead Tt region)
    convW<<<dim3(KFC / 32, HDIM / 32), dim3(32, 8), 0, stream>>>(wf1, Wt);

    // G4: fc1 partials, split-K=16 (M=1024, N=512, K=1568/slice -> 512 blocks)
    gemm_bt<2><<<dim3(HDIM / BN, BATCH / BM, KS_FC), 256, 0, stream>>>(
        h2f, KFC, Wt, KFC, (KFC / KS_FC) / BK, KFC / KS_FC,
        (size_t)BATCH * HDIM, part, HDIM, nullptr, nullptr);

    // fc1 reduce + relu + fc2 + softmax
    fc2_softmax<<<BATCH / 4, 256, 0, stream>>>(part, bf1, wf2, bf2, out);
}

// Round 4
// 301.548 us; speedup vs baseline: 2.0164x; 2.0164x over previous
//
#include <hip/hip_runtime.h>
#include <hip/hip_bf16.h>
#include <math.h>

// Problem constants
#define BATCH 1024
#define NREAL 784
#define NPAD  896      // 7*128, zero-padded graph dim
#define C1D   32
#define C2D   32
#define HDIM  512
#define NCLS  10
#define KFC   25088    // 784*32

#define KS_G1 7        // split-K for G1 (K=896 -> 128/slice, 4 iters, EVEN)
#define KS_FC 14       // split-K for fc1 (K=25088 -> 1792/slice, 56 iters, EVEN)

// GEMM tile
#define BM 128
#define BN 128
#define BK 32

using bf16x8  = __attribute__((ext_vector_type(8))) __bf16;
using floatx4 = __attribute__((ext_vector_type(4))) float;

__device__ __forceinline__ float elu_f(float t) {
    return t > 0.f ? t : (__expf(t) - 1.f);
}

// LDS-only barrier: waits ds ops but leaves global loads (vmcnt) in flight.
// __syncthreads() would emit s_waitcnt vmcnt(0) and drain the prefetch queue.
__device__ __forceinline__ void wg_barrier_lds() {
    asm volatile("s_waitcnt lgkmcnt(0)\n\ts_barrier" ::: "memory");
}

// ---------------------------------------------------------------------------
// BT-GEMM, register-staged pipeline (spill-proof version: every staging reg
// is an individually named int4; no dynamic indexing; kIters MUST be even).
//   global_load_dwordx4 (prefetch distance 2, in flight across barriers)
//     -> named VGPRs -> ds_write_b128 -> LDS dbuf -> ds_read_b128 -> MFMA
// One lgkm-only barrier per k-iter. C[row][col] = sum_k A[row][k]*Bm[col][k].
// 128x128 tile, 256 thr (4 waves, 2x2 of 64x64), BK=32, mfma 16x16x32 bf16.
// MODE 1: elu(acc+bias[col&31]) -> bf16 outH[(col>>5)*KFC+row*32+(col&31)],
//         masked to row<784                                           (G3)
// MODE 2: fp32 partial store outF[z*sliceStride + row*ldc + col]   (G1, G4)
// ---------------------------------------------------------------------------
template<int MODE>
__launch_bounds__(256)
__global__ void gemm_bt(const __hip_bfloat16* __restrict__ A, int lda,
                        const __hip_bfloat16* __restrict__ Bm, int ldb,
                        int kIters, int kPerZ, size_t sliceStride,
                        float* __restrict__ outF, int ldc,
                        __hip_bfloat16* __restrict__ outH,
                        const float* __restrict__ bias)
{
    __shared__ __align__(16) __hip_bfloat16 As[2][BM * BK];
    __shared__ __align__(16) __hip_bfloat16 Bs[2][BN * BK];

    const int tid  = threadIdx.x;
    const int lane = tid & 63;
    const int wave = tid >> 6;
    const int wi = wave >> 1, wj = wave & 1;

    const int m0 = blockIdx.y * BM;
    const int n0 = blockIdx.x * BN;
    const int kBase = blockIdx.z * kPerZ;

    const int rowInChunk = lane >> 2;       // 16 rows per 1KB chunk
    const int kOff8 = (lane & 3) * 8;       // 4 lanes cover 32 bf16 per row

    // per-thread global source pointers (advance by BK each stage)
    const __hip_bfloat16* aSrc0 = A  + (size_t)(m0 + (wave * 2 + 0) * 16 + rowInChunk) * lda + kBase + kOff8;
    const __hip_bfloat16* aSrc1 = A  + (size_t)(m0 + (wave * 2 + 1) * 16 + rowInChunk) * lda + kBase + kOff8;
    const __hip_bfloat16* bSrc0 = Bm + (size_t)(n0 + (wave * 2 + 0) * 16 + rowInChunk) * ldb + kBase + kOff8;
    const __hip_bfloat16* bSrc1 = Bm + (size_t)(n0 + (wave * 2 + 1) * 16 + rowInChunk) * ldb + kBase + kOff8;
    // per-thread LDS write offsets (elements): chunk*512 + lane*8
    const int ldsW0 = (wave * 2 + 0) * 512 + lane * 8;
    const int ldsW1 = (wave * 2 + 1) * 512 + lane * 8;

    floatx4 acc[4][4];
    const floatx4 zero4 = {0.f, 0.f, 0.f, 0.f};
    #pragma unroll
    for (int i = 0; i < 4; i++)
        #pragma unroll
        for (int j = 0; j < 4; j++) acc[i][j] = zero4;

    // staging register sets (named scalars -> guaranteed VGPRs, no scratch)
    int4 aA0, aA1, bA0, bA1;   // set A (even stages)
    int4 aB0, aB1, bB0, bB1;   // set B (odd stages)

    // prologue: load stage 0 (set A) and stage 1 (set B); write stage 0 to buf 0
    aA0 = *(const int4*)aSrc0; aA1 = *(const int4*)aSrc1;
    bA0 = *(const int4*)bSrc0; bA1 = *(const int4*)bSrc1;
    aSrc0 += BK; aSrc1 += BK; bSrc0 += BK; bSrc1 += BK;
    aB0 = *(const int4*)aSrc0; aB1 = *(const int4*)aSrc1;
    bB0 = *(const int4*)bSrc0; bB1 = *(const int4*)bSrc1;
    aSrc0 += BK; aSrc1 += BK; bSrc0 += BK; bSrc1 += BK;

    *(int4*)(&As[0][ldsW0]) = aA0;
    *(int4*)(&As[0][ldsW1]) = aA1;
    *(int4*)(&Bs[0][ldsW0]) = bA0;
    *(int4*)(&Bs[0][ldsW1]) = bA1;
    wg_barrier_lds();

    for (int kt = 0; kt < kIters; kt += 2) {
        const bool more = (kt + 2 < kIters);

        // ======== u = 0: compute stage kt from buf 0 ========
        {
            bf16x8 af[4], bfr[4];
            #pragma unroll
            for (int mi = 0; mi < 4; mi++)
                af[mi] = *(const bf16x8*)(&As[0][(wi * 64 + mi * 16 + (lane & 15)) * BK + (lane >> 4) * 8]);
            #pragma unroll
            for (int nj = 0; nj < 4; nj++)
                bfr[nj] = *(const bf16x8*)(&Bs[0][(wj * 64 + nj * 16 + (lane & 15)) * BK + (lane >> 4) * 8]);

            if (more) {   // prefetch stage kt+2 into set A
                aA0 = *(const int4*)aSrc0; aA1 = *(const int4*)aSrc1;
                bA0 = *(const int4*)bSrc0; bA1 = *(const int4*)bSrc1;
                aSrc0 += BK; aSrc1 += BK; bSrc0 += BK; bSrc1 += BK;
            }
            // stage kt+1 (set B) -> buf 1 (compiler inserts fine-grained vmcnt)
            *(int4*)(&As[1][ldsW0]) = aB0;
            *(int4*)(&As[1][ldsW1]) = aB1;
            *(int4*)(&Bs[1][ldsW0]) = bB0;
            *(int4*)(&Bs[1][ldsW1]) = bB1;

            #pragma unroll
            for (int mi = 0; mi < 4; mi++)
                #pragma unroll
                for (int nj = 0; nj < 4; nj++)
                    acc[mi][nj] = __builtin_amdgcn_mfma_f32_16x16x32_bf16(af[mi], bfr[nj], acc[mi][nj], 0, 0, 0);

            wg_barrier_lds();   // all waves done reading buf0 + buf1 now visible
        }

        // ======== u = 1: compute stage kt+1 from buf 1 ========
        {
            bf16x8 af[4], bfr[4];
            #pragma unroll
            for (int mi = 0; mi < 4; mi++)
                af[mi] = *(const bf16x8*)(&As[1][(wi * 64 + mi * 16 + (lane & 15)) * BK + (lane >> 4) * 8]);
            #pragma unroll
            for (int nj = 0; nj < 4; nj++)
                bfr[nj] = *(const bf16x8*)(&Bs[1][(wj * 64 + nj * 16 + (lane & 15)) * BK + (lane >> 4) * 8]);

            if (more) {   // prefetch stage kt+3 into set B
                aB0 = *(const int4*)aSrc0; aB1 = *(const int4*)aSrc1;
                bB0 = *(const int4*)bSrc0; bB1 = *(const int4*)bSrc1;
                aSrc0 += BK; aSrc1 += BK; bSrc0 += BK; bSrc1 += BK;
                // stage kt+2 (set A) -> buf 0 (safe: barrier above covered buf0 reads)
                *(int4*)(&As[0][ldsW0]) = aA0;
                *(int4*)(&As[0][ldsW1]) = aA1;
                *(int4*)(&Bs[0][ldsW0]) = bA0;
                *(int4*)(&Bs[0][ldsW1]) = bA1;
            }

            #pragma unroll
            for (int mi = 0; mi < 4; mi++)
                #pragma unroll
                for (int nj = 0; nj < 4; nj++)
                    acc[mi][nj] = __builtin_amdgcn_mfma_f32_16x16x32_bf16(af[mi], bfr[nj], acc[mi][nj], 0, 0, 0);

            wg_barrier_lds();
        }
    }

    // epilogue: C/D layout col=lane&15, row=(lane>>4)*4+reg  [verified m89/m91]
    #pragma unroll
    for (int mi = 0; mi < 4; mi++) {
        #pragma unroll
        for (int nj = 0; nj < 4; nj++) {
            #pragma unroll
            for (int r = 0; r < 4; r++) {
                const int row = m0 + wi * 64 + mi * 16 + (lane >> 4) * 4 + r;
                const int col = n0 + wj * 64 + nj * 16 + (lane & 15);
                const float v = acc[mi][nj][r];
                if (MODE == 1) {
                    if (row < NREAL) {
                        const int c = col & 31, b = col >> 5;
                        const float t = elu_f(v + bias[c]);
                        outH[(size_t)b * KFC + row * 32 + c] = __float2bfloat16(t);
                    }
                } else {
                    outF[(size_t)blockIdx.z * sliceStride + (size_t)row * ldc + col] = v;
                }
            }
        }
    }
}

// ---------------------------------------------------------------------------
// Conversions / padding
// ---------------------------------------------------------------------------
__global__ void convX(const float* __restrict__ x, __hip_bfloat16* __restrict__ Xbf) {
    const int idx = blockIdx.x * 256 + threadIdx.x;
    if (idx >= BATCH * NPAD) return;
    const int m = idx % NPAD, b = idx / NPAD;
    const float v = (m < NREAL) ? x[(size_t)b * NREAL + m] : 0.f;
    Xbf[idx] = __float2bfloat16(v);
}

__global__ void convA(const float* __restrict__ a, __hip_bfloat16* __restrict__ Abf) {
    const int idx = blockIdx.x * 256 + threadIdx.x;
    if (idx >= NPAD * NPAD) return;
    const int m = idx % NPAD, n = idx / NPAD;
    const float v = (m < NREAL && n < NREAL) ? a[(size_t)n * NREAL + m] : 0.f;
    Abf[idx] = __float2bfloat16(v);
}

// wf1 [25088][512] fp32 -> Wt [512][25088] bf16 (LDS tile transpose)
__global__ void convW(const float* __restrict__ wf1, __hip_bfloat16* __restrict__ Wt) {
    __shared__ float tile[32][33];
    const int k0 = blockIdx.x * 32, h0 = blockIdx.y * 32;
    const int tx = threadIdx.x, ty = threadIdx.y;  // (32,8)
    #pragma unroll
    for (int i = 0; i < 4; i++)
        tile[ty * 4 + i][tx] = wf1[(size_t)(k0 + ty * 4 + i) * HDIM + h0 + tx];
    __syncthreads();
    #pragma unroll
    for (int i = 0; i < 4; i++)
        Wt[(size_t)(h0 + ty * 4 + i) * KFC + k0 + tx] = __float2bfloat16(tile[tx][ty * 4 + i]);
}

// ---------------------------------------------------------------------------
// Layer-1 fused pointwise: reduce KS_G1 Y split-K partials, then
// T_t[(b*32+c)][m] = sum_c' elu(Y[b][m]*w1[c']+b1[c'])*W2[c'][c]
// ---------------------------------------------------------------------------
__global__ void layer1_fuse(const float* __restrict__ Ypart,
                            const float* __restrict__ w1, const float* __restrict__ b1,
                            const float* __restrict__ w2,
                            __hip_bfloat16* __restrict__ Tt)
{
    __shared__ __align__(16) float sW2[C1D * C2D];
    __shared__ float sw1[C1D], sb1[C1D];
    const int tid = threadIdx.x;                 // 128 threads
    for (int i = tid; i < C1D * C2D; i += 128) sW2[i] = w2[i];
    if (tid < C1D) { sw1[tid] = w1[tid]; sb1[tid] = b1[tid]; }
    __syncthreads();

    const int m = blockIdx.x * 128 + tid;        // 0..895
    const int b = blockIdx.y;
    float y = 0.f;
    #pragma unroll
    for (int z = 0; z < KS_G1; z++)
        y += Ypart[(size_t)z * (BATCH * NPAD) + (size_t)b * NPAD + m];

    float h[C1D];
    #pragma unroll
    for (int c1 = 0; c1 < C1D; c1++) h[c1] = elu_f(y * sw1[c1] + sb1[c1]);

    float4 t4[8];
    #pragma unroll
    for (int q = 0; q < 8; q++) t4[q] = make_float4(0.f, 0.f, 0.f, 0.f);
    #pragma unroll
    for (int c1 = 0; c1 < C1D; c1++) {
        const float hv = h[c1];
        const float4* row = (const float4*)(sW2 + c1 * C2D);
        #pragma unroll
        for (int q = 0; q < 8; q++) {
            const float4 w = row[q];
            t4[q].x += hv * w.x; t4[q].y += hv * w.y;
            t4[q].z += hv * w.z; t4[q].w += hv * w.w;
        }
    }
    const float* tf = (const float*)t4;
    #pragma unroll
    for (int c = 0; c < C2D; c++)
        Tt[((size_t)(b * 32 + c)) * NPAD + m] = __float2bfloat16(tf[c]);
}

// ---------------------------------------------------------------------------
// fc1 reduce (split-K partials) + relu + fc2 + softmax, fused.
// One wave per batch row; lane covers 8 h-values.
// ---------------------------------------------------------------------------
__global__ void fc2_softmax(const float* __restrict__ part, const float* __restrict__ bf1,
                            const float* __restrict__ wf2, const float* __restrict__ bf2,
                            float* __restrict__ out)
{
    __shared__ float sW[HDIM * NCLS];
    __shared__ float sb[NCLS];
    const int tid = threadIdx.x;                 // 256
    for (int i = tid; i < HDIM * NCLS; i += 256) sW[i] = wf2[i];
    if (tid < NCLS) sb[tid] = bf2[tid];
    __syncthreads();

    const int lane = tid & 63, wave = tid >> 6;
    const int b = blockIdx.x * 4 + wave;

    float acc[NCLS];
    #pragma unroll
    for (int c = 0; c < NCLS; c++) acc[c] = 0.f;
    #pragma unroll
    for (int q = 0; q < 8; q++) {
        const int h = q * 64 + lane;
        float hv = bf1[h];
        #pragma unroll
        for (int z = 0; z < KS_FC; z++)
            hv += part[(size_t)z * (BATCH * HDIM) + (size_t)b * HDIM + h];
        hv = hv > 0.f ? hv : 0.f;
        #pragma unroll
        for (int c = 0; c < NCLS; c++) acc[c] += hv * sW[h * NCLS + c];
    }
    #pragma unroll
    for (int c = 0; c < NCLS; c++) {
        #pragma unroll
        for (int off = 32; off >= 1; off >>= 1) acc[c] += __shfl_down(acc[c], off);
    }
    if (lane == 0) {
        float mx = -1e30f;
        #pragma unroll
        for (int c = 0; c < NCLS; c++) { acc[c] += sb[c]; mx = fmaxf(mx, acc[c]); }
        float e[NCLS], s = 0.f;
        #pragma unroll
        for (int c = 0; c < NCLS; c++) { e[c] = __expf(acc[c] - mx); s += e[c]; }
        const float inv = 1.f / s;
        #pragma unroll
        for (int c = 0; c < NCLS; c++) out[(size_t)b * NCLS + c] = e[c] * inv;
    }
}

// ---------------------------------------------------------------------------
// Workspace layout (peak ~113.5 MB)
//   h2f   [0,          51380224)  bf16 1024x25088  (written G3, read G4)
//     Ypart [0, 25690112) f32 7x1024x896 — overlay, dead before G3 writes h2f
//   Tt    [51380224,  110100480)  bf16 32768x896   (dead after G3)
//     Wt   [51380224, 77070336)   bf16 512x25088 — overlay after G3
//     part [77070336, 106430464)  f32 14x1024x512 — overlay after G3
//   Abf   [110100480, 111706112)  bf16 896x896
//   Xbf   [111706112, 113541120)  bf16 1024x896    (dead after G1)
// ---------------------------------------------------------------------------
extern "C" void kernel_launch(void* const* d_in, const int* in_sizes, int n_in,
                              void* d_out, int out_size, void* d_ws, size_t ws_size,
                              hipStream_t stream)
{
    const float* x   = (const float*)d_in[0];
    const float* a   = (const float*)d_in[1];
    const float* w1  = (const float*)d_in[2];
    const float* b1  = (const float*)d_in[3];
    const float* w2  = (const float*)d_in[4];
    const float* b2  = (const float*)d_in[5];
    const float* wf1 = (const float*)d_in[6];
    const float* bf1 = (const float*)d_in[7];
    const float* wf2 = (const float*)d_in[8];
    const float* bf2 = (const float*)d_in[9];
    float* out = (float*)d_out;

    char* ws = (char*)d_ws;
    __hip_bfloat16* h2f  = (__hip_bfloat16*)(ws + 0);
    float*          Ypart= (float*)(ws + 0);                  // overlay (pre-G3)
    __hip_bfloat16* Tt   = (__hip_bfloat16*)(ws + 51380224);
    __hip_bfloat16* Wt   = (__hip_bfloat16*)(ws + 51380224);  // overlay (post-G3)
    float*          part = (float*)(ws + 77070336);           // overlay (post-G3)
    __hip_bfloat16* Abf  = (__hip_bfloat16*)(ws + 110100480);
    __hip_bfloat16* Xbf  = (__hip_bfloat16*)(ws + 111706112);

    convX<<<(BATCH * NPAD + 255) / 256, 256, 0, stream>>>(x, Xbf);
    convA<<<(NPAD * NPAD + 255) / 256, 256, 0, stream>>>(a, Abf);

    // G1: Ypart[z][b][n] partials of sum_m Xbf[b][m]*Abf[n][m]
    //     (M=1024, N=896, K=128/slice, split-K=7 -> 392 blocks, 4 iters EVEN)
    gemm_bt<2><<<dim3(NPAD / BN, BATCH / BM, KS_G1), 256, 0, stream>>>(
        Xbf, NPAD, Abf, NPAD, (NPAD / KS_G1) / BK, NPAD / KS_G1,
        (size_t)BATCH * NPAD, Ypart, NPAD, nullptr, nullptr);

    // layer-1 pointwise + @W2, transposed store (reduces Ypart internally)
    layer1_fuse<<<dim3(NPAD / 128, BATCH), 128, 0, stream>>>(Ypart, w1, b1, w2, Tt);

    // G3: h2 = elu(A @ T + b2);  C[n][(b,c)] (M=896, N=32768, K=896 -> 1792 blocks, 28 iters EVEN)
    gemm_bt<1><<<dim3((BATCH * 32) / BN, NPAD / BM, 1), 256, 0, stream>>>(
        Abf, NPAD, Tt, NPAD, NPAD / BK, 0, 0, nullptr, 0, h2f, b2);

    // transpose wf1 -> bf16 (into the now-dead Tt region)
    convW<<<dim3(KFC / 32, HDIM / 32), dim3(32, 8), 0, stream>>>(wf1, Wt);

    // G4: fc1 partials, split-K=14 (M=1024, N=512, K=1792/slice -> 448 blocks, 56 iters EVEN)
    gemm_bt<2><<<dim3(HDIM / BN, BATCH / BM, KS_FC), 256, 0, stream>>>(
        h2f, KFC, Wt, KFC, (KFC / KS_FC) / BK, KFC / KS_FC,
        (size_t)BATCH * HDIM, part, HDIM, nullptr, nullptr);

    // fc1 reduce + relu + fc2 + softmax
    fc2_softmax<<<BATCH / 4, 256, 0, stream>>>(part, bf1, wf2, bf2, out);
}

// Round 5
// 300.060 us; speedup vs baseline: 2.0264x; 1.0050x over previous
//
#include <hip/hip_runtime.h>
#include <hip/hip_bf16.h>
#include <math.h>

// Problem constants
#define BATCH 1024
#define NREAL 784
#define NPAD  896      // 7*128, zero-padded graph dim
#define C1D   32
#define C2D   32
#define HDIM  512
#define NCLS  10
#define KFC   25088    // 784*32

#define KS_G1 7        // split-K for G1 (K=896 -> 128/slice, 4 iters, EVEN)
#define KS_FC 14       // split-K for fc1 (K=25088 -> 1792/slice, 56 iters, EVEN)

// GEMM tile
#define BM 128
#define BN 128
#define BK 32

using bf16x8  = __attribute__((ext_vector_type(8))) __bf16;
using floatx4 = __attribute__((ext_vector_type(4))) float;

__device__ __forceinline__ float elu_f(float t) {
    return t > 0.f ? t : (__expf(t) - 1.f);
}

// LDS-only barrier: waits ds ops but leaves global loads (vmcnt) in flight.
// __syncthreads() would emit s_waitcnt vmcnt(0) and drain the prefetch queue.
__device__ __forceinline__ void wg_barrier_lds() {
    asm volatile("s_waitcnt lgkmcnt(0)\n\ts_barrier" ::: "memory");
}

// ---------------------------------------------------------------------------
// BT-GEMM, register-staged pipeline + XOR-swizzled LDS layout.
//
// LDS layout: element (row, k) lives at row*32 + slot(row,k>>3)*8 + (k&7),
// slot(row,q) = (q + ((row>>1)&3)) & 3.  Un-swizzled, ds_read_b128 (byte
// stride 64/row) hits only 8 of 32 banks per 16-lane phase (~4-way conflict,
// SQ_LDS_BANK_CONFLICT = 4/read in r4).  Swizzled: writes perfect, reads
// 2-way (free, m136).
//
//   global_load_dwordx4 (prefetch distance 2, in flight across barriers)
//     -> named VGPRs -> ds_write_b128 -> LDS dbuf -> ds_read_b128 -> MFMA
// One lgkm-only barrier per k-iter. C[row][col] = sum_k A[row][k]*Bm[col][k].
// kIters MUST be even. 128x128 tile, 4 waves (2x2 of 64x64), mfma 16x16x32.
// MODE 1: elu(acc+bias[col&31]) -> bf16 outH[(col>>5)*KFC+row*32+(col&31)],
//         masked to row<784                                           (G3)
// MODE 2: fp32 partial store outF[z*sliceStride + row*ldc + col]   (G1, G4)
// ---------------------------------------------------------------------------
template<int MODE>
__launch_bounds__(256)
__global__ void gemm_bt(const __hip_bfloat16* __restrict__ A, int lda,
                        const __hip_bfloat16* __restrict__ Bm, int ldb,
                        int kIters, int kPerZ, size_t sliceStride,
                        float* __restrict__ outF, int ldc,
                        __hip_bfloat16* __restrict__ outH,
                        const float* __restrict__ bias)
{
    __shared__ __align__(16) __hip_bfloat16 As[2][BM * BK];
    __shared__ __align__(16) __hip_bfloat16 Bs[2][BN * BK];

    const int tid  = threadIdx.x;
    const int lane = tid & 63;
    const int wave = tid >> 6;
    const int wi = wave >> 1, wj = wave & 1;

    const int m0 = blockIdx.y * BM;
    const int n0 = blockIdx.x * BN;
    const int kBase = blockIdx.z * kPerZ;

    const int rowInChunk = lane >> 2;       // 16 rows per 1KB chunk
    const int kOff8 = (lane & 3) * 8;       // 4 lanes cover 32 bf16 per row

    // per-thread global source pointers (advance by BK each stage)
    const __hip_bfloat16* aSrc0 = A  + (size_t)(m0 + (wave * 2 + 0) * 16 + rowInChunk) * lda + kBase + kOff8;
    const __hip_bfloat16* aSrc1 = A  + (size_t)(m0 + (wave * 2 + 1) * 16 + rowInChunk) * lda + kBase + kOff8;
    const __hip_bfloat16* bSrc0 = Bm + (size_t)(n0 + (wave * 2 + 0) * 16 + rowInChunk) * ldb + kBase + kOff8;
    const __hip_bfloat16* bSrc1 = Bm + (size_t)(n0 + (wave * 2 + 1) * 16 + rowInChunk) * ldb + kBase + kOff8;

    // swizzled LDS write offsets (elements). row within chunk = lane>>2;
    // (row>>1)&3 == (lane>>3)&3 for every chunk (chunk*16 is 0 mod 8).
    const int wSlot = (((lane & 3) + ((lane >> 3) & 3)) & 3) * 8;
    const int ldsW0 = (wave * 2 + 0) * 512 + rowInChunk * 32 + wSlot;
    const int ldsW1 = ldsW0 + 512;

    // swizzled LDS read k-offset: logical k-group q = lane>>4, row low = lane&15
    const int rSlot = ((((lane >> 4) + (((lane & 15) >> 1) & 3)) & 3)) * 8;
    const int rRow  = lane & 15;

    floatx4 acc[4][4];
    const floatx4 zero4 = {0.f, 0.f, 0.f, 0.f};
    #pragma unroll
    for (int i = 0; i < 4; i++)
        #pragma unroll
        for (int j = 0; j < 4; j++) acc[i][j] = zero4;

    // staging register sets (named scalars -> guaranteed VGPRs, no scratch)
    int4 aA0, aA1, bA0, bA1;   // set A (even stages)
    int4 aB0, aB1, bB0, bB1;   // set B (odd stages)

    // prologue: load stage 0 (set A) and stage 1 (set B); write stage 0 to buf 0
    aA0 = *(const int4*)aSrc0; aA1 = *(const int4*)aSrc1;
    bA0 = *(const int4*)bSrc0; bA1 = *(const int4*)bSrc1;
    aSrc0 += BK; aSrc1 += BK; bSrc0 += BK; bSrc1 += BK;
    aB0 = *(const int4*)aSrc0; aB1 = *(const int4*)aSrc1;
    bB0 = *(const int4*)bSrc0; bB1 = *(const int4*)bSrc1;
    aSrc0 += BK; aSrc1 += BK; bSrc0 += BK; bSrc1 += BK;

    *(int4*)(&As[0][ldsW0]) = aA0;
    *(int4*)(&As[0][ldsW1]) = aA1;
    *(int4*)(&Bs[0][ldsW0]) = bA0;
    *(int4*)(&Bs[0][ldsW1]) = bA1;
    wg_barrier_lds();

    for (int kt = 0; kt < kIters; kt += 2) {
        const bool more = (kt + 2 < kIters);

        // ======== u = 0: compute stage kt from buf 0 ========
        {
            bf16x8 af[4], bfr[4];
            #pragma unroll
            for (int mi = 0; mi < 4; mi++)
                af[mi] = *(const bf16x8*)(&As[0][(wi * 64 + mi * 16 + rRow) * BK + rSlot]);
            #pragma unroll
            for (int nj = 0; nj < 4; nj++)
                bfr[nj] = *(const bf16x8*)(&Bs[0][(wj * 64 + nj * 16 + rRow) * BK + rSlot]);

            if (more) {   // prefetch stage kt+2 into set A
                aA0 = *(const int4*)aSrc0; aA1 = *(const int4*)aSrc1;
                bA0 = *(const int4*)bSrc0; bA1 = *(const int4*)bSrc1;
                aSrc0 += BK; aSrc1 += BK; bSrc0 += BK; bSrc1 += BK;
            }
            // stage kt+1 (set B) -> buf 1 (compiler inserts fine-grained vmcnt)
            *(int4*)(&As[1][ldsW0]) = aB0;
            *(int4*)(&As[1][ldsW1]) = aB1;
            *(int4*)(&Bs[1][ldsW0]) = bB0;
            *(int4*)(&Bs[1][ldsW1]) = bB1;

            #pragma unroll
            for (int mi = 0; mi < 4; mi++)
                #pragma unroll
                for (int nj = 0; nj < 4; nj++)
                    acc[mi][nj] = __builtin_amdgcn_mfma_f32_16x16x32_bf16(af[mi], bfr[nj], acc[mi][nj], 0, 0, 0);

            wg_barrier_lds();   // all waves done reading buf0 + buf1 now visible
        }

        // ======== u = 1: compute stage kt+1 from buf 1 ========
        {
            bf16x8 af[4], bfr[4];
            #pragma unroll
            for (int mi = 0; mi < 4; mi++)
                af[mi] = *(const bf16x8*)(&As[1][(wi * 64 + mi * 16 + rRow) * BK + rSlot]);
            #pragma unroll
            for (int nj = 0; nj < 4; nj++)
                bfr[nj] = *(const bf16x8*)(&Bs[1][(wj * 64 + nj * 16 + rRow) * BK + rSlot]);

            if (more) {   // prefetch stage kt+3 into set B
                aB0 = *(const int4*)aSrc0; aB1 = *(const int4*)aSrc1;
                bB0 = *(const int4*)bSrc0; bB1 = *(const int4*)bSrc1;
                aSrc0 += BK; aSrc1 += BK; bSrc0 += BK; bSrc1 += BK;
                // stage kt+2 (set A) -> buf 0 (safe: barrier above covered buf0 reads)
                *(int4*)(&As[0][ldsW0]) = aA0;
                *(int4*)(&As[0][ldsW1]) = aA1;
                *(int4*)(&Bs[0][ldsW0]) = bA0;
                *(int4*)(&Bs[0][ldsW1]) = bA1;
            }

            #pragma unroll
            for (int mi = 0; mi < 4; mi++)
                #pragma unroll
                for (int nj = 0; nj < 4; nj++)
                    acc[mi][nj] = __builtin_amdgcn_mfma_f32_16x16x32_bf16(af[mi], bfr[nj], acc[mi][nj], 0, 0, 0);

            wg_barrier_lds();
        }
    }

    // epilogue: C/D layout col=lane&15, row=(lane>>4)*4+reg  [verified m89/m91]
    #pragma unroll
    for (int mi = 0; mi < 4; mi++) {
        #pragma unroll
        for (int nj = 0; nj < 4; nj++) {
            #pragma unroll
            for (int r = 0; r < 4; r++) {
                const int row = m0 + wi * 64 + mi * 16 + (lane >> 4) * 4 + r;
                const int col = n0 + wj * 64 + nj * 16 + (lane & 15);
                const float v = acc[mi][nj][r];
                if (MODE == 1) {
                    if (row < NREAL) {
                        const int c = col & 31, b = col >> 5;
                        const float t = elu_f(v + bias[c]);
                        outH[(size_t)b * KFC + row * 32 + c] = __float2bfloat16(t);
                    }
                } else {
                    outF[(size_t)blockIdx.z * sliceStride + (size_t)row * ldc + col] = v;
                }
            }
        }
    }
}

// ---------------------------------------------------------------------------
// Conversions / padding
// ---------------------------------------------------------------------------
__global__ void convX(const float* __restrict__ x, __hip_bfloat16* __restrict__ Xbf) {
    const int idx = blockIdx.x * 256 + threadIdx.x;
    if (idx >= BATCH * NPAD) return;
    const int m = idx % NPAD, b = idx / NPAD;
    const float v = (m < NREAL) ? x[(size_t)b * NREAL + m] : 0.f;
    Xbf[idx] = __float2bfloat16(v);
}

__global__ void convA(const float* __restrict__ a, __hip_bfloat16* __restrict__ Abf) {
    const int idx = blockIdx.x * 256 + threadIdx.x;
    if (idx >= NPAD * NPAD) return;
    const int m = idx % NPAD, n = idx / NPAD;
    const float v = (m < NREAL && n < NREAL) ? a[(size_t)n * NREAL + m] : 0.f;
    Abf[idx] = __float2bfloat16(v);
}

// wf1 [25088][512] fp32 -> Wt [512][25088] bf16 (LDS tile transpose)
__global__ void convW(const float* __restrict__ wf1, __hip_bfloat16* __restrict__ Wt) {
    __shared__ float tile[32][33];
    const int k0 = blockIdx.x * 32, h0 = blockIdx.y * 32;
    const int tx = threadIdx.x, ty = threadIdx.y;  // (32,8)
    #pragma unroll
    for (int i = 0; i < 4; i++)
        tile[ty * 4 + i][tx] = wf1[(size_t)(k0 + ty * 4 + i) * HDIM + h0 + tx];
    __syncthreads();
    #pragma unroll
    for (int i = 0; i < 4; i++)
        Wt[(size_t)(h0 + ty * 4 + i) * KFC + k0 + tx] = __float2bfloat16(tile[tx][ty * 4 + i]);
}

// ---------------------------------------------------------------------------
// Layer-1 fused pointwise: reduce KS_G1 Y split-K partials, then
// T_t[(b*32+c)][m] = sum_c' elu(Y[b][m]*w1[c']+b1[c'])*W2[c'][c]
// ---------------------------------------------------------------------------
__global__ void layer1_fuse(const float* __restrict__ Ypart,
                            const float* __restrict__ w1, const float* __restrict__ b1,
                            const float* __restrict__ w2,
                            __hip_bfloat16* __restrict__ Tt)
{
    __shared__ __align__(16) float sW2[C1D * C2D];
    __shared__ float sw1[C1D], sb1[C1D];
    const int tid = threadIdx.x;                 // 128 threads
    for (int i = tid; i < C1D * C2D; i += 128) sW2[i] = w2[i];
    if (tid < C1D) { sw1[tid] = w1[tid]; sb1[tid] = b1[tid]; }
    __syncthreads();

    const int m = blockIdx.x * 128 + tid;        // 0..895
    const int b = blockIdx.y;
    float y = 0.f;
    #pragma unroll
    for (int z = 0; z < KS_G1; z++)
        y += Ypart[(size_t)z * (BATCH * NPAD) + (size_t)b * NPAD + m];

    float h[C1D];
    #pragma unroll
    for (int c1 = 0; c1 < C1D; c1++) h[c1] = elu_f(y * sw1[c1] + sb1[c1]);

    float4 t4[8];
    #pragma unroll
    for (int q = 0; q < 8; q++) t4[q] = make_float4(0.f, 0.f, 0.f, 0.f);
    #pragma unroll
    for (int c1 = 0; c1 < C1D; c1++) {
        const float hv = h[c1];
        const float4* row = (const float4*)(sW2 + c1 * C2D);
        #pragma unroll
        for (int q = 0; q < 8; q++) {
            const float4 w = row[q];
            t4[q].x += hv * w.x; t4[q].y += hv * w.y;
            t4[q].z += hv * w.z; t4[q].w += hv * w.w;
        }
    }
    const float* tf = (const float*)t4;
    #pragma unroll
    for (int c = 0; c < C2D; c++)
        Tt[((size_t)(b * 32 + c)) * NPAD + m] = __float2bfloat16(tf[c]);
}

// ---------------------------------------------------------------------------
// fc1 reduce (split-K partials) + relu + fc2 + softmax, fused.
// One wave per batch row; lane covers 8 h-values.
// ---------------------------------------------------------------------------
__global__ void fc2_softmax(const float* __restrict__ part, const float* __restrict__ bf1,
                            const float* __restrict__ wf2, const float* __restrict__ bf2,
                            float* __restrict__ out)
{
    __shared__ float sW[HDIM * NCLS];
    __shared__ float sb[NCLS];
    const int tid = threadIdx.x;                 // 256
    for (int i = tid; i < HDIM * NCLS; i += 256) sW[i] = wf2[i];
    if (tid < NCLS) sb[tid] = bf2[tid];
    __syncthreads();

    const int lane = tid & 63, wave = tid >> 6;
    const int b = blockIdx.x * 4 + wave;

    float acc[NCLS];
    #pragma unroll
    for (int c = 0; c < NCLS; c++) acc[c] = 0.f;
    #pragma unroll
    for (int q = 0; q < 8; q++) {
        const int h = q * 64 + lane;
        float hv = bf1[h];
        #pragma unroll
        for (int z = 0; z < KS_FC; z++)
            hv += part[(size_t)z * (BATCH * HDIM) + (size_t)b * HDIM + h];
        hv = hv > 0.f ? hv : 0.f;
        #pragma unroll
        for (int c = 0; c < NCLS; c++) acc[c] += hv * sW[h * NCLS + c];
    }
    #pragma unroll
    for (int c = 0; c < NCLS; c++) {
        #pragma unroll
        for (int off = 32; off >= 1; off >>= 1) acc[c] += __shfl_down(acc[c], off);
    }
    if (lane == 0) {
        float mx = -1e30f;
        #pragma unroll
        for (int c = 0; c < NCLS; c++) { acc[c] += sb[c]; mx = fmaxf(mx, acc[c]); }
        float e[NCLS], s = 0.f;
        #pragma unroll
        for (int c = 0; c < NCLS; c++) { e[c] = __expf(acc[c] - mx); s += e[c]; }
        const float inv = 1.f / s;
        #pragma unroll
        for (int c = 0; c < NCLS; c++) out[(size_t)b * NCLS + c] = e[c] * inv;
    }
}

// ---------------------------------------------------------------------------
// Workspace layout (peak ~113.5 MB)
//   h2f   [0,          51380224)  bf16 1024x25088  (written G3, read G4)
//     Ypart [0, 25690112) f32 7x1024x896 — overlay, dead before G3 writes h2f
//   Tt    [51380224,  110100480)  bf16 32768x896   (dead after G3)
//     Wt   [51380224, 77070336)   bf16 512x25088 — overlay after G3
//     part [77070336, 106430464)  f32 14x1024x512 — overlay after G3
//   Abf   [110100480, 111706112)  bf16 896x896
//   Xbf   [111706112, 113541120)  bf16 1024x896    (dead after G1)
// ---------------------------------------------------------------------------
extern "C" void kernel_launch(void* const* d_in, const int* in_sizes, int n_in,
                              void* d_out, int out_size, void* d_ws, size_t ws_size,
                              hipStream_t stream)
{
    const float* x   = (const float*)d_in[0];
    const float* a   = (const float*)d_in[1];
    const float* w1  = (const float*)d_in[2];
    const float* b1  = (const float*)d_in[3];
    const float* w2  = (const float*)d_in[4];
    const float* b2  = (const float*)d_in[5];
    const float* wf1 = (const float*)d_in[6];
    const float* bf1 = (const float*)d_in[7];
    const float* wf2 = (const float*)d_in[8];
    const float* bf2 = (const float*)d_in[9];
    float* out = (float*)d_out;

    char* ws = (char*)d_ws;
    __hip_bfloat16* h2f  = (__hip_bfloat16*)(ws + 0);
    float*          Ypart= (float*)(ws + 0);                  // overlay (pre-G3)
    __hip_bfloat16* Tt   = (__hip_bfloat16*)(ws + 51380224);
    __hip_bfloat16* Wt   = (__hip_bfloat16*)(ws + 51380224);  // overlay (post-G3)
    float*          part = (float*)(ws + 77070336);           // overlay (post-G3)
    __hip_bfloat16* Abf  = (__hip_bfloat16*)(ws + 110100480);
    __hip_bfloat16* Xbf  = (__hip_bfloat16*)(ws + 111706112);

    convX<<<(BATCH * NPAD + 255) / 256, 256, 0, stream>>>(x, Xbf);
    convA<<<(NPAD * NPAD + 255) / 256, 256, 0, stream>>>(a, Abf);

    // G1: Ypart[z][b][n] partials of sum_m Xbf[b][m]*Abf[n][m]
    //     (M=1024, N=896, K=128/slice, split-K=7 -> 392 blocks, 4 iters EVEN)
    gemm_bt<2><<<dim3(NPAD / BN, BATCH / BM, KS_G1), 256, 0, stream>>>(
        Xbf, NPAD, Abf, NPAD, (NPAD / KS_G1) / BK, NPAD / KS_G1,
        (size_t)BATCH * NPAD, Ypart, NPAD, nullptr, nullptr);

    // layer-1 pointwise + @W2, transposed store (reduces Ypart internally)
    layer1_fuse<<<dim3(NPAD / 128, BATCH), 128, 0, stream>>>(Ypart, w1, b1, w2, Tt);

    // G3: h2 = elu(A @ T + b2);  C[n][(b,c)] (M=896, N=32768, K=896 -> 1792 blocks, 28 iters EVEN)
    gemm_bt<1><<<dim3((BATCH * 32) / BN, NPAD / BM, 1), 256, 0, stream>>>(
        Abf, NPAD, Tt, NPAD, NPAD / BK, 0, 0, nullptr, 0, h2f, b2);

    // transpose wf1 -> bf16 (into the now-dead Tt region)
    convW<<<dim3(KFC / 32, HDIM / 32), dim3(32, 8), 0, stream>>>(wf1, Wt);

    // G4: fc1 partials, split-K=14 (M=1024, N=512, K=1792/slice -> 448 blocks, 56 iters EVEN)
    gemm_bt<2><<<dim3(HDIM / BN, BATCH / BM, KS_FC), 256, 0, stream>>>(
        h2f, KFC, Wt, KFC, (KFC / KS_FC) / BK, KFC / KS_FC,
        (size_t)BATCH * HDIM, part, HDIM, nullptr, nullptr);

    // fc1 reduce + relu + fc2 + softmax
    fc2_softmax<<<BATCH / 4, 256, 0, stream>>>(part, bf1, wf2, bf2, out);
}